// Round 5
// baseline (161.401 us; speedup 1.0000x reference)
//
#include <hip/hip_runtime.h>
#include <math.h>

#define Bn 32
#define Pn 32768
#define On 32
#define TPB 256
#define PPT 4                 // priors per thread in matchB
#define BP  (TPB * PPT)       // priors per matchB block = 1024
#define APB 1024              // priors per matchA block (64 lanes x 16)

// d_ws layout:
// [0,     8192)  u64   bpm[Bn*On]   packed (iou_bits<<32 | (Pn-1-p)) per (b,o)
// [8192,  8320)  int   num_pos[Bn]
// [8320,  8324)  float loss_l_total
// [8324,  8328)  float ce_total
// [8328,  8332)  int   np_total
// [8332,  8336)  uint  tick (topk completion ticket)
// [16384, 16384+4*Bn*Pn) float ce_mine[Bn*Pn]

__device__ __forceinline__ unsigned long long shfl_down_u64(unsigned long long v, int off) {
    unsigned lo = (unsigned)(v & 0xFFFFFFFFull);
    unsigned hi = (unsigned)(v >> 32);
    lo = __shfl_down(lo, off, 64);
    hi = __shfl_down(hi, off, 64);
    return ((unsigned long long)hi << 32) | lo;
}

// ---------------- Phase A: per-(b,o) argmax_p IoU ----------------
// grid (Pn/APB, Bn), 256 threads. Each lane owns 16 priors in registers;
// each wave handles 8 targets (4 waves x 8 = 32). All 8 key-reduces are
// batched at the end so the 6-level shuffle chains interleave (one
// latency-chain instead of eight). Lane 0 -> 8 global atomicMax.
__global__ __launch_bounds__(256) void matchA(const float4* __restrict__ priors,
                                              const float* __restrict__ targets,
                                              unsigned long long* __restrict__ bpm) {
    int b    = blockIdx.y;
    int base = blockIdx.x * APB;
    int tid  = threadIdx.x;
    int lane = tid & 63, wv = tid >> 6;

    __shared__ float4 tb[On];
    __shared__ float  ta[On];

    if (tid < On) {
        const float* t = targets + ((size_t)b * On + tid) * 5;
        float x1 = t[0], y1 = t[1], x2 = t[2], y2 = t[3];
        tb[tid] = make_float4(x1, y1, x2, y2);
        ta[tid] = (x2 - x1) * (y2 - y1);
    }

    // lane owns priors p = base + lane + 64*i, i ascending -> p ascending
    float px1[16], py1[16], px2[16], py2[16], ab[16];
#pragma unroll
    for (int i = 0; i < 16; i++) {
        float4 pr = priors[base + lane + 64 * i];
        px1[i] = pr.x - pr.z * 0.5f; py1[i] = pr.y - pr.w * 0.5f;
        px2[i] = pr.x + pr.z * 0.5f; py2[i] = pr.y + pr.w * 0.5f;
        ab[i]  = (px2[i] - px1[i]) * (py2[i] - py1[i]);
    }
    __syncthreads();

    unsigned long long key[8];
#pragma unroll
    for (int t = 0; t < 8; t++) {
        int o = wv * 8 + t;
        float4 tt = tb[o];
        float  a  = ta[o];
        float bI = 0.f, bU = 1.f;
        int   bi = 0;
#pragma unroll
        for (int i = 0; i < 16; i++) {
            float ix1 = fmaxf(tt.x, px1[i]), iy1 = fmaxf(tt.y, py1[i]);
            float ix2 = fminf(tt.z, px2[i]), iy2 = fminf(tt.w, py2[i]);
            float iw = fmaxf(ix2 - ix1, 0.f), ih = fmaxf(iy2 - iy1, 0.f);
            float I = iw * ih;
            float U = a + ab[i] - I;
            if (I * bU > bI * U) { bI = I; bU = U; bi = i; }
        }
        int p = base + lane + 64 * bi;
        float iou = bI / bU;                 // IEEE divide: reference key rounding
        key[t] = ((unsigned long long)__float_as_uint(iou) << 32)
               | (unsigned)(Pn - 1 - p);
    }

    // interleaved 6-level wave max-reduce of all 8 keys at once
#pragma unroll
    for (int off = 32; off > 0; off >>= 1) {
        unsigned long long other[8];
#pragma unroll
        for (int t = 0; t < 8; t++) other[t] = shfl_down_u64(key[t], off);
#pragma unroll
        for (int t = 0; t < 8; t++) if (other[t] > key[t]) key[t] = other[t];
    }
    if (lane == 0) {
#pragma unroll
        for (int t = 0; t < 8; t++)
            atomicMax(&bpm[b * On + wv * 8 + t], key[t]);
    }
}

// ------- Phase B: per-prior matching, loc loss, CE, ce_mine -------
// grid (Pn/BP, Bn), 256 threads, PPT=4 priors/thread (strided by 256).
// (unchanged from the verified 51-us version)
__global__ __launch_bounds__(256) void matchB(const float* __restrict__ loc,
                                              const float2* __restrict__ conf2,
                                              const float4* __restrict__ priors,
                                              const float* __restrict__ targets,
                                              const unsigned long long* __restrict__ bpm,
                                              float* __restrict__ ce_mine,
                                              int* __restrict__ num_pos,
                                              float* __restrict__ loss_l_t,
                                              float* __restrict__ ce_t,
                                              int* __restrict__ np_tot) {
    int b = blockIdx.y;
    int base = blockIdx.x * BP;
    int tid = threadIdx.x;

    // prefetch conf2 first thing: latency hides under the whole o-loop
    float2 cc[PPT];
#pragma unroll
    for (int j = 0; j < PPT; j++) cc[j] = conf2[(size_t)b * Pn + base + tid + 256 * j];

    __shared__ float4 tb[On];
    __shared__ float  ta[On], lb[On];
    __shared__ int    forced[BP];    // truth index forcing this prior, else -1
    __shared__ float  sred[12];

#pragma unroll
    for (int j = 0; j < PPT; j++) forced[tid + 256 * j] = -1;
    int sp = -1;
    if (tid < On) {
        const float* t = targets + ((size_t)b * On + tid) * 5;
        float x1 = t[0], y1 = t[1], x2 = t[2], y2 = t[3];
        tb[tid] = make_float4(x1, y1, x2, y2);
        ta[tid] = (x2 - x1) * (y2 - y1);
        lb[tid] = t[4];
        sp = Pn - 1 - (int)(bpm[b * On + tid] & 0xFFFFFFFFull);
    }
    __syncthreads();            // forced[] init complete
    if (tid < On && sp >= base && sp < base + BP)
        atomicMax(&forced[sp - base], tid);   // duplicate bpi: max o == numpy last-write
    __syncthreads();

    float px1[PPT], py1[PPT], px2[PPT], py2[PPT], ab[PPT], pcx[PPT], pcy[PPT], pw[PPT], ph[PPT];
#pragma unroll
    for (int j = 0; j < PPT; j++) {
        float4 pr = priors[base + tid + 256 * j];
        pcx[j] = pr.x; pcy[j] = pr.y; pw[j] = pr.z; ph[j] = pr.w;
        px1[j] = pr.x - pr.z * 0.5f; py1[j] = pr.y - pr.w * 0.5f;
        px2[j] = pr.x + pr.z * 0.5f; py2[j] = pr.y + pr.w * 0.5f;
        ab[j]  = (px2[j] - px1[j]) * (py2[j] - py1[j]);
    }

    // two independent 16-long chains per prior (h = o/16), merged after.
    float bIc[PPT][2], bUc[PPT][2];
    int   bxc[PPT][2];
#pragma unroll
    for (int j = 0; j < PPT; j++)
#pragma unroll
        for (int h = 0; h < 2; h++) { bIc[j][h] = 0.f; bUc[j][h] = 1.f; bxc[j][h] = h * 16; }

#pragma unroll 2
    for (int o16 = 0; o16 < 16; o16++) {
#pragma unroll
        for (int h = 0; h < 2; h++) {
            int o = h * 16 + o16;
            float4 tt = tb[o];
            float  a  = ta[o];
#pragma unroll
            for (int j = 0; j < PPT; j++) {
                float ix1 = fmaxf(tt.x, px1[j]), iy1 = fmaxf(tt.y, py1[j]);
                float ix2 = fminf(tt.z, px2[j]), iy2 = fminf(tt.w, py2[j]);
                float iw = fmaxf(ix2 - ix1, 0.f), ih = fmaxf(iy2 - iy1, 0.f);
                float I = iw * ih;
                float U = a + ab[j] - I;
                if (I * bUc[j][h] > bIc[j][h] * U) { bIc[j][h] = I; bUc[j][h] = U; bxc[j][h] = o; }
            }
        }
    }
    // merge: chain1 wins only if strictly greater -> earliest-o tie semantics kept
    float bI[PPT], bU[PPT];
    int   bx[PPT];
#pragma unroll
    for (int j = 0; j < PPT; j++) {
        bI[j] = bIc[j][0]; bU[j] = bUc[j][0]; bx[j] = bxc[j][0];
        if (bIc[j][1] * bU[j] > bI[j] * bUc[j][1]) { bI[j] = bIc[j][1]; bU[j] = bUc[j][1]; bx[j] = bxc[j][1]; }
    }

    float ll_s = 0.f, pce_s = 0.f, cnt_s = 0.f;
#pragma unroll
    for (int j = 0; j < PPT; j++) {
        int p = base + tid + 256 * j;
        int fo = forced[tid + 256 * j];
        int bidx = (fo >= 0) ? fo : bx[j];
        int cf;
        if (fo >= 0)                      cf = (int)lb[bidx];
        else if (bI[j] >= 0.5f * bU[j])   cf = (int)lb[bidx];
        else                              cf = 0;
        bool pos = cf > 0;

        if (pos) {
            float4 tt = tb[bidx];
            float g0 = ((tt.x + tt.z) * 0.5f - pcx[j]) / (0.1f * pw[j]);
            float g1 = ((tt.y + tt.w) * 0.5f - pcy[j]) / (0.1f * ph[j]);
            float g2 = __logf((tt.z - tt.x) / pw[j]) * 5.0f;
            float g3 = __logf((tt.w - tt.y) / ph[j]) * 5.0f;
            const float* lp = loc + ((size_t)b * Pn + p) * 3;
            float q0 = lp[0], q1 = lp[1], q2 = lp[2];
            float dd[4] = { q0 - g0, q1 - g1, q2 - g2, q2 - g3 };
#pragma unroll
            for (int i = 0; i < 4; i++) {
                float ad = fabsf(dd[i]);
                ll_s += (ad < 1.f) ? 0.5f * dd[i] * dd[i] : (ad - 0.5f);
            }
            cnt_s += 1.f;
        }

        float m = fmaxf(cc[j].x, cc[j].y);
        float lse = m + __logf(__expf(cc[j].x - m) + __expf(cc[j].y - m));
        float ce = lse - (cf ? cc[j].y : cc[j].x);     // >= 0
        if (pos) { pce_s += ce; ce = 0.f; }
        ce_mine[(size_t)b * Pn + p] = fmaxf(ce, 0.f);
    }

    // fused 3-value block reduce
#pragma unroll
    for (int off = 32; off > 0; off >>= 1) {
        ll_s  += __shfl_down(ll_s,  off, 64);
        pce_s += __shfl_down(pce_s, off, 64);
        cnt_s += __shfl_down(cnt_s, off, 64);
    }
    int lane = tid & 63, wv = tid >> 6;
    if (lane == 0) { sred[wv * 3] = ll_s; sred[wv * 3 + 1] = pce_s; sred[wv * 3 + 2] = cnt_s; }
    __syncthreads();
    if (tid == 0) {
        float llr = 0, pcer = 0, cntr = 0;
        for (int w = 0; w < 4; w++) { llr += sred[w*3]; pcer += sred[w*3+1]; cntr += sred[w*3+2]; }
        if (llr != 0.f)  atomicAdd(loss_l_t, llr);
        if (pcer != 0.f) atomicAdd(ce_t, pcer);
        int c = (int)cntr;
        if (c) { atomicAdd(&num_pos[b], c); atomicAdd(np_tot, c); }
    }
}

// ---- Phase C: exact top-k sum via 3-round radix histogram select ----
// One block per batch, 1024 threads, 32 values/thread in VGPRs.
// Radix 9+11+11. Per-round epilogue collapsed to a single wave-0 pass:
// lane sums its bin range, one shuffle suffix-scan, crossing lane walks
// its bins down and writes s_lo/s_ab. 3 barriers/round, no u64 merges.
// Last block to finish finalizes the output (ticket counter).
__global__ __launch_bounds__(1024) void topk(const float* __restrict__ ce_mine,
                                             const int* __restrict__ num_pos,
                                             float* __restrict__ ce_t,
                                             const float* __restrict__ loss_l_t,
                                             const int* __restrict__ np_tot,
                                             unsigned* __restrict__ tick,
                                             float* __restrict__ out) {
    int b = blockIdx.x, tid = threadIdx.x;
    const float4* v4 = (const float4*)(ce_mine + (size_t)b * Pn);
    float4 r[8];
#pragma unroll
    for (int i = 0; i < 8; i++) r[i] = v4[i * 1024 + tid];

    int k = 3 * num_pos[b];
    if (k > Pn - 1) k = Pn - 1;

    __shared__ int hist[8192];                // 4 sub-hists x 2048 bins (32KB)
    __shared__ unsigned s_lo;
    __shared__ int s_ab;
    __shared__ float ssum[16];
    __shared__ int   scnt[16];

    int lane = tid & 63, wv = tid >> 6;

    if (k > 0) {                              // uniform across block
        unsigned LO = 0u;
        int AB = 0;                           // count(u >= bracket top)

        const int SH[3] = {22, 11, 0};
        const int NB[3] = {512, 2048, 2048};

#pragma unroll
        for (int rd = 0; rd < 3; rd++) {
            int shift = SH[rd], nb = NB[rd];
#pragma unroll
            for (int i = 0; i < 8; i++) hist[tid + 1024 * i] = 0;
            __syncthreads();
            int* myh = hist + ((wv >> 2) << 11);   // 4-way sub-hist
#pragma unroll
            for (int i = 0; i < 8; i++) {
                float4 rv = r[i];
                float vals[4] = {rv.x, rv.y, rv.z, rv.w};
#pragma unroll
                for (int q = 0; q < 4; q++) {
                    unsigned u = __float_as_uint(vals[q]);
                    unsigned bin = (u - LO) >> shift;        // underflow -> huge -> skipped
                    if (bin < (unsigned)nb) atomicAdd(&myh[bin], 1);
                }
            }
            __syncthreads();
            if (wv == 0) {
                int bpl = nb >> 6;            // bins per lane: 8 or 32
                int bb = lane * bpl;
                int lsum = 0;
                for (int q = 0; q < bpl; q++) {
                    int bin = bb + q;
                    lsum += hist[bin] + hist[2048 + bin] + hist[4096 + bin] + hist[6144 + bin];
                }
                // inclusive suffix-scan over lanes: suf = count(bins >= bb)
                int suf = lsum;
#pragma unroll
                for (int off = 1; off < 64; off <<= 1) {
                    int o = __shfl(suf, (lane + off) & 63, 64);
                    suf += ((lane + off) < 64) ? o : 0;
                }
                int kk = k - AB;              // >= 1 by invariant
                if (suf >= kk && (suf - lsum) < kk) {   // crossing lane (unique)
                    int acc = suf - lsum;     // count(bins >= bb+bpl)
                    for (int q = bpl - 1; q >= 0; q--) {
                        int bin = bb + q;
                        int hc = hist[bin] + hist[2048 + bin] + hist[4096 + bin] + hist[6144 + bin];
                        acc += hc;            // = count(bins >= bb+q)
                        if (acc >= kk) {
                            s_lo = LO + ((unsigned)bin << shift);
                            s_ab = AB + (acc - hc);
                            break;
                        }
                    }
                }
            }
            __syncthreads();
            LO = s_lo; AB = s_ab;
        }
        // final bracket width 1: tau bits == LO; count(> tau) = AB < k <= count(>= tau)
        float tau = __uint_as_float(LO);
        float s = 0.f; int c = 0;
#pragma unroll
        for (int i = 0; i < 8; i++) {
            if (r[i].x > tau) { s += r[i].x; c++; }
            if (r[i].y > tau) { s += r[i].y; c++; }
            if (r[i].z > tau) { s += r[i].z; c++; }
            if (r[i].w > tau) { s += r[i].w; c++; }
        }
#pragma unroll
        for (int off = 32; off > 0; off >>= 1) {
            s += __shfl_down(s, off, 64);
            c += __shfl_down(c, off, 64);
        }
        if (lane == 0) { ssum[wv] = s; scnt[wv] = c; }
        __syncthreads();
        if (tid == 0) {
            float st = 0.f; int ct = 0;
            for (int w = 0; w < 16; w++) { st += ssum[w]; ct += scnt[w]; }
            atomicAdd(ce_t, st + (float)(k - ct) * tau);   // ties at tau, tie-agnostic exact
        }
    }

    // ticket: last block finalizes (device-scope atomics; adds happen-before ticket)
    if (tid == 0) {
        __threadfence();
        unsigned done = atomicAdd(tick, 1u);
        if (done == (unsigned)(Bn - 1)) {
            float N  = (float)atomicAdd((int*)np_tot, 0);
            float ll = atomicAdd((float*)loss_l_t, 0.f);
            float ce = atomicAdd(ce_t, 0.f);
            out[0] = ll / N;
            out[1] = ce / N;
        }
    }
}

extern "C" void kernel_launch(void* const* d_in, const int* in_sizes, int n_in,
                              void* d_out, int out_size, void* d_ws, size_t ws_size,
                              hipStream_t stream) {
    const float* loc     = (const float*)d_in[0];  // (B,P,3)
    const float* conf    = (const float*)d_in[1];  // (B,P,2)
    const float* priors  = (const float*)d_in[2];  // (P,4)
    const float* targets = (const float*)d_in[3];  // (B,O,5)
    float* out = (float*)d_out;

    char* ws = (char*)d_ws;
    unsigned long long* bpm = (unsigned long long*)ws;
    int*   num_pos  = (int*)(ws + 8192);
    float* loss_l_t = (float*)(ws + 8320);
    float* ce_t     = (float*)(ws + 8324);
    int*   np_tot   = (int*)(ws + 8328);
    unsigned* tick  = (unsigned*)(ws + 8332);
    float* ce_mine  = (float*)(ws + 16384);

    hipMemsetAsync(ws, 0, 16384, stream);

    hipLaunchKernelGGL(matchA, dim3(Pn / APB, Bn), dim3(256), 0, stream,
                       (const float4*)priors, targets, bpm);
    hipLaunchKernelGGL(matchB, dim3(Pn / BP, Bn), dim3(256), 0, stream,
                       loc, (const float2*)conf, (const float4*)priors, targets, bpm,
                       ce_mine, num_pos, loss_l_t, ce_t, np_tot);
    hipLaunchKernelGGL(topk, dim3(Bn), dim3(1024), 0, stream,
                       ce_mine, num_pos, ce_t, loss_l_t, np_tot, tick, out);
}